// Round 14
// baseline (99.617 us; speedup 1.0000x reference)
//
#include <hip/hip_runtime.h>
#include <hip/hip_bf16.h>

typedef __attribute__((ext_vector_type(8))) short bf16x8;
typedef __attribute__((ext_vector_type(4))) float f32x4;
typedef __attribute__((ext_vector_type(4))) unsigned int u32x4;
typedef unsigned short u16;
typedef unsigned int u32;

static constexpr int KDIM  = 784;   // 28*28
static constexpr int KP    = 800;   // K padded (weff zero-pads k>=784 and n>=300)
static constexpr int NDIM  = 300;
static constexpr int NP    = 320;
static constexpr int DDIM  = 10;
static constexpr int BM    = 256;   // rows per block -> grid = 256 = 1 block/CU
static constexpr int BK    = 32;
static constexpr int NSTEP = 25;
static constexpr int H1STR = 328;
static constexpr int NROW  = 65536;
static constexpr int NTHR  = 512;   // 8 waves: 2m x 4n (wave tile 128x80)
// LDS layout (bytes): A fp32 3 x 32768 @ 0..98304; B bf16 2 x 20480 @ 98304..139264.
static constexpr int ABYTES = 32768;
static constexpr int BBASEU = 49152; // u16 offset of B region (= 98304 B)
static constexpr int BU     = 10240; // u16 per B buffer (= 20480 B)

__device__ __forceinline__ u16 f2bf(float f) {
  unsigned u = __builtin_bit_cast(unsigned, f);
  u += 0x7fffu + ((u >> 16) & 1u);   // RNE
  return (u16)(u >> 16);
}
__device__ __forceinline__ u32 pk2(float a, float b) {
  u32 r;
  asm("v_cvt_pk_bf16_f32 %0, %1, %2" : "=v"(r) : "v"(a), "v"(b));
  return r;
}
__device__ __forceinline__ void gll16(const void* g, void* l) {
  __builtin_amdgcn_global_load_lds(
      (const __attribute__((address_space(1))) void*)g,
      (__attribute__((address_space(3))) void*)l, 16, 0, 0);
}

// ---- Kernel A: fold conv into first linear layer; weff_t[n][k] bf16, zero-padded.
// One block per image row r (28 blocks). The <=3x26 w1 rows needed (78x300 fp32)
// staged in LDS with fully-coalesced loads; outputs via an LDS tile.
__global__ void __launch_bounds__(256)
build_weff(const float* __restrict__ cw, const float* __restrict__ w1,
           u16* __restrict__ weff) {
  __shared__ float w1s[78 * 300];     // 93600 B: image rows (r-2..r) x 26oc x 300n
  __shared__ u16 outT[NP * 28];       // [n][c] 17920 B  (total 111520 B)

  const int r   = blockIdx.x;
  const int tid = threadIdx.x;

  for (int i = tid; i < 3 * 7800; i += 256) {
    int j = i / 7800, rem = i - j * 7800;
    int orr = r - 2 + j;
    w1s[i] = ((unsigned)orr < 26u) ? w1[orr * 7800 + rem] : 0.f;
  }
  float c9[9];
  #pragma unroll
  for (int q = 0; q < 9; ++q) c9[q] = cw[q];
  __syncthreads();

  for (int i = tid; i < NP * 28; i += 256) {
    int n = i / 28, c = i - (i / 28) * 28;
    float acc = 0.f;
    if (n < NDIM) {
      #pragma unroll
      for (int dr = 0; dr < 3; ++dr) {
        int orr = r - dr;                 // LDS j = orr-(r-2) = 2-dr
        if ((unsigned)orr < 26u) {
          #pragma unroll
          for (int dc = 0; dc < 3; ++dc) {
            int oc = c - dc;
            if ((unsigned)oc < 26u)
              acc += c9[dr * 3 + dc] * w1s[((2 - dr) * 26 + oc) * 300 + n];
          }
        }
      }
    }
    outT[i] = f2bf(acc);
  }
  __syncthreads();

  for (int i = tid; i < NP * 28; i += 256) {
    int n = i / 28, c = i - (i / 28) * 28;
    weff[n * KP + r * 28 + c] = outT[i];
  }
  if (r == 27) {                        // zero-pad k = 784..799 for all n
    for (int i = tid; i < NP * 16; i += 256) {
      int n = i / 16, kk = 784 + (i - (i / 16) * 16);
      weff[n * KP + kk] = (u16)0;
    }
  }
}

// ---- Kernel B: out = relu(x @ Weff + b1) @ w2 + b2 ----
// K-loop identical to r9 (proven 61.7us): 3 A buffers staged 2 ahead,
// counted vmcnt(4) keeps A(t+2) in flight across every barrier.
// 512 thr / 8 waves (2m x 4n); wave tile 128 x 80 (acc = 8x5 frags).
__global__ void __launch_bounds__(NTHR, 2)
fused_mlp(const float* __restrict__ x, const float* __restrict__ b1,
          const float* __restrict__ w2, const float* __restrict__ b2,
          const u16* __restrict__ weff, float* __restrict__ out) {
  __shared__ __align__(16) u16 lds[69632];   // 139264 B -> 1 block/CU

  const int tid  = threadIdx.x;
  const int wv   = tid >> 6;
  const int lane = tid & 63;
  const int l16  = lane & 15;
  const int lhi  = lane >> 4;     // 0..3
  const int wm   = wv >> 2;       // 0..1 -> rows wm*128
  const int wn   = wv & 3;        // 0..3 -> cols wn*80
  const int bm   = blockIdx.x * BM;
  const int wvn  = wn * 80;

  // A staging (4 chunks/thread): slot s in [0,2048), row=s>>3 (8x16B/row),
  // global chunk qg = (s&7) ^ (row&7)   (line-coalesced + bank-even)
  int aRow[4], aQg[4];
  #pragma unroll
  for (int it = 0; it < 4; ++it) {
    int s = tid + it * NTHR;
    aRow[it] = s >> 3;
    aQg[it]  = (s & 7) ^ (aRow[it] & 7);
  }
  // B staging (3 chunks/thread; slots 1024..1279 double-written benignly):
  int bRow[3], bQg[3], bSlot[3];
  #pragma unroll
  for (int i = 0; i < 3; ++i) {
    int s = (i < 2) ? (tid + i * NTHR) : (1024 + (tid & 255));
    bSlot[i] = s;
    bRow[i]  = s >> 2;
    bQg[i]   = (s & 3) ^ (bRow[i] & 3);
  }

  auto stageA = [&](int bufi, int t) {
    char* base = (char*)lds + bufi * ABYTES;
    int k0 = (t < NSTEP) ? t * BK : 0;   // dummy stages keep vmcnt uniform
    #pragma unroll
    for (int it = 0; it < 4; ++it) {
      int kof = k0 + aQg[it] * 4;
      if (kof >= KDIM) kof = aQg[it] * 4;   // tail: finite garbage, B zero-pad
      gll16(x + (size_t)(bm + aRow[it]) * KDIM + kof,
            base + (tid + it * NTHR) * 16);
    }
  };
  auto stageB = [&](int bufi, int t) {
    char* base = (char*)(lds + BBASEU + bufi * BU);
    int k0 = (t < NSTEP) ? t * BK : 0;
    #pragma unroll
    for (int i = 0; i < 3; ++i)
      gll16(weff + (size_t)bRow[i] * KP + k0 + bQg[i] * 8, base + bSlot[i] * 16);
  };

  f32x4 acc[8][5];
  #pragma unroll
  for (int mi = 0; mi < 8; ++mi)
    #pragma unroll
    for (int ni = 0; ni < 5; ++ni)
      acc[mi][ni] = (f32x4){0.f, 0.f, 0.f, 0.f};

  auto compute = [&](int abufi, int bbufi) {
    const f32x4* Af = (const f32x4*)((char*)lds + abufi * ABYTES);
    const u16*   Bb = lds + BBASEU + bbufi * BU;
    bf16x8 bfr[5];
    #pragma unroll
    for (int ni = 0; ni < 5; ++ni) {
      int n = wvn + ni * 16 + l16;
      int slot = n * 4 + (lhi ^ (n & 3));
      bfr[ni] = *reinterpret_cast<const bf16x8*>(Bb + slot * 8);
    }
    #pragma unroll
    for (int mi = 0; mi < 8; ++mi) {
      int R = wm * 128 + mi * 16 + l16;
      f32x4 a0 = Af[R * 8 + ((2 * lhi)     ^ (R & 7))];
      f32x4 a1 = Af[R * 8 + ((2 * lhi + 1) ^ (R & 7))];
      u32x4 amu = { pk2(a0[0], a0[1]), pk2(a0[2], a0[3]),
                    pk2(a1[0], a1[1]), pk2(a1[2], a1[3]) };
      bf16x8 am = __builtin_bit_cast(bf16x8, amu);
      #pragma unroll
      for (int ni = 0; ni < 5; ++ni)
        acc[mi][ni] = __builtin_amdgcn_mfma_f32_16x16x32_bf16(am, bfr[ni], acc[mi][ni], 0, 0, 0);
    }
  };

  // ---- prologue (r9): A(0),B(0),A(1); drain A(0)+B(0); keep A(1) in flight ----
  stageA(0, 0);
  stageB(0, 0);
  stageA(1, 1);
  asm volatile("s_waitcnt vmcnt(4)" ::: "memory");
  __builtin_amdgcn_s_barrier();
  __builtin_amdgcn_sched_barrier(0);

  // ---- main loop (r9): 25 steps, one barrier/step, A(t+2) always in flight ----
  for (int t = 0; t < NSTEP; ++t) {
    stageB((t + 1) & 1, t + 1);        // 3 gll (dummy at t=24)
    stageA((t + 2) % 3, t + 2);        // 4 gll (dummies at tail)
    __builtin_amdgcn_sched_barrier(0);
    compute(t % 3, t & 1);
    __builtin_amdgcn_sched_barrier(0);
    asm volatile("s_waitcnt vmcnt(4)" ::: "memory");  // drain A(t+1),B(t+1); keep A(t+2)
    __builtin_amdgcn_s_barrier();
    __builtin_amdgcn_sched_barrier(0);
  }
  __syncthreads();    // full drain (incl. dummy stages) before LDS overlay

  // ---- epilogue: h1 = relu(acc + b1); out = h1 @ w2 + b2, 2 passes of 128 rows ----
  u16* H1  = lds;                  // [128][328] = 41984 u16 (83968 B)
  u16* W2T = lds + 128 * H1STR;    // [16][328] = 5248 u16 (ends 94464 B <= 139264)

  for (int i = tid; i < 16 * NP; i += NTHR) {
    int d = i / NP, n = i - (i / NP) * NP;
    float v = (d < DDIM && n < NDIM) ? w2[n * DDIM + d] : 0.f;
    W2T[d * H1STR + n] = f2bf(v);
  }
  float biasv[5];
  #pragma unroll
  for (int ni = 0; ni < 5; ++ni) {
    int col = wvn + ni * 16 + l16;
    biasv[ni] = (col < NDIM) ? b1[col] : 0.f;
  }

  #pragma unroll
  for (int p = 0; p < 2; ++p) {
    if (wm == p) {                     // this wm-half writes its full 128 rows
      #pragma unroll
      for (int mi = 0; mi < 8; ++mi) {
        #pragma unroll
        for (int ni = 0; ni < 5; ++ni) {
          int col = wvn + ni * 16 + l16;
          int rb  = mi * 16 + lhi * 4;
          #pragma unroll
          for (int r = 0; r < 4; ++r) {
            float h = acc[mi][ni][r] + biasv[ni];
            H1[(rb + r) * H1STR + col] = f2bf(fmaxf(h, 0.f));
          }
        }
      }
    }
    __syncthreads();                   // H1 (and W2T on p==0) visible
    {                                  // all 8 waves: 16 rows each
      f32x4 a2c = (f32x4){0.f, 0.f, 0.f, 0.f};
      #pragma unroll
      for (int ks = 0; ks < NP / 32; ++ks) {
        bf16x8 a2 = *reinterpret_cast<const bf16x8*>(
            H1 + (wv * 16 + l16) * H1STR + ks * 32 + lhi * 8);
        bf16x8 bw = *reinterpret_cast<const bf16x8*>(
            W2T + l16 * H1STR + ks * 32 + lhi * 8);
        a2c = __builtin_amdgcn_mfma_f32_16x16x32_bf16(a2, bw, a2c, 0, 0, 0);
      }
      if (l16 < DDIM) {
        float bb = b2[l16];
        #pragma unroll
        for (int r = 0; r < 4; ++r) {
          int row = bm + p * 128 + wv * 16 + lhi * 4 + r;
          out[(size_t)row * DDIM + l16] = a2c[r] + bb;
        }
      }
    }
    __syncthreads();                   // before next pass overwrites H1
  }
}

extern "C" void kernel_launch(void* const* d_in, const int* in_sizes, int n_in,
                              void* d_out, int out_size, void* d_ws, size_t ws_size,
                              hipStream_t stream) {
  const float* x  = (const float*)d_in[0];
  const float* cw = (const float*)d_in[1];
  const float* w1 = (const float*)d_in[2];
  const float* b1 = (const float*)d_in[3];
  const float* w2 = (const float*)d_in[4];
  const float* b2 = (const float*)d_in[5];
  float* out = (float*)d_out;
  u16* weff = (u16*)d_ws;   // 320*800*2 = 512000 bytes

  hipLaunchKernelGGL(build_weff, dim3(28), dim3(256), 0, stream, cw, w1, weff);
  hipLaunchKernelGGL(fused_mlp, dim3(NROW / BM), dim3(NTHR), 0, stream,
                     x, b1, w2, b2, weff, out);
}

// Round 15
// 89.160 us; speedup vs baseline: 1.1173x; 1.1173x over previous
//
#include <hip/hip_runtime.h>
#include <hip/hip_bf16.h>

typedef __attribute__((ext_vector_type(8))) short bf16x8;
typedef __attribute__((ext_vector_type(4))) float f32x4;
typedef __attribute__((ext_vector_type(4))) unsigned int u32x4;
typedef unsigned short u16;
typedef unsigned int u32;

static constexpr int KDIM  = 784;   // 28*28
static constexpr int KP    = 800;   // K padded (weff zero-pads k>=784 and n>=300)
static constexpr int NDIM  = 300;
static constexpr int NP    = 320;
static constexpr int DDIM  = 10;
static constexpr int BM    = 128;   // rows per block -> grid 512 = 2 blocks/CU
static constexpr int BK    = 32;
static constexpr int NSTEP = 25;
static constexpr int H1STR = 328;
static constexpr int NROW  = 65536;
static constexpr int NTHR  = 256;   // 4 waves, 1m x 4n (wave tile 128x80)
// LDS (u16 units): A bf16 3 x [128][36] = 3*4608 @ 0; B 2 x 10240 @ 13824.
static constexpr int ASTR  = 36;    // 32 + 4 pad (bank-spread, ~2-way max)
static constexpr int AU    = 128 * ASTR;   // 4608 u16 / buffer
static constexpr int BBASEU= 3 * AU;       // 13824 u16
static constexpr int BU    = 10240;        // u16 / B buffer
// total = 13824 + 20480 = 34304 u16 = 68608 B -> 2 blocks/CU

__device__ __forceinline__ u16 f2bf(float f) {
  unsigned u = __builtin_bit_cast(unsigned, f);
  u += 0x7fffu + ((u >> 16) & 1u);   // RNE
  return (u16)(u >> 16);
}
__device__ __forceinline__ u32 pk2(float a, float b) {
  u32 r;
  asm("v_cvt_pk_bf16_f32 %0, %1, %2" : "=v"(r) : "v"(a), "v"(b));
  return r;
}
__device__ __forceinline__ void gll16(const void* g, void* l) {
  __builtin_amdgcn_global_load_lds(
      (const __attribute__((address_space(1))) void*)g,
      (__attribute__((address_space(3))) void*)l, 16, 0, 0);
}

// ---- Kernel A: original proven version (part of the 61.7us measurement) ----
__global__ void build_weff(const float* __restrict__ cw,
                           const float* __restrict__ w1,
                           u16* __restrict__ weff) {
  int idx = blockIdx.x * 256 + threadIdx.x;
  if (idx >= NP * KP) return;
  int n = idx / KP;
  int k = idx - n * KP;
  float acc = 0.f;
  if (n < NDIM && k < KDIM) {
    int r = k / 28, c = k - (k / 28) * 28;
    #pragma unroll
    for (int dr = 0; dr < 3; ++dr) {
      int orr = r - dr;
      if ((unsigned)orr < 26u) {
        #pragma unroll
        for (int dc = 0; dc < 3; ++dc) {
          int oc = c - dc;
          if ((unsigned)oc < 26u)
            acc += cw[dr * 3 + dc] * w1[(orr * 26 + oc) * NDIM + n];
        }
      }
    }
  }
  weff[n * KP + k] = f2bf(acc);
}

// ---- Kernel B: out = relu(x @ Weff + b1) @ w2 + b2 ----
// 256 thr / 4 waves (1m x 4n); wave tile 128 x 80 (acc = 8x5 = 160 regs).
// Grid 512 = 2 blocks/CU (cross-block overlap of barrier/drain time).
// A: bf16 in LDS. global->reg (t+2, a full-step latency budget) -> pk2 ->
//    ds_write at end of step t. Halves A LDS bytes + fragment reads vs fp32.
// B: gll 2-deep, 1 step ahead (L2-resident weff), r9's proven XOR layout.
// In-order vmcnt: [4 A-loads][5 B-gll] ... vmcnt(5) drains exactly the A
// loads; vmcnt(0) pre-barrier finds B long since landed.
__global__ void __launch_bounds__(NTHR, 2)
fused_mlp(const float* __restrict__ x, const float* __restrict__ b1,
          const float* __restrict__ w2, const float* __restrict__ b2,
          const u16* __restrict__ weff, float* __restrict__ out) {
  __shared__ __align__(16) u16 lds[34304];   // 68608 B

  const int tid  = threadIdx.x;
  const int wv   = tid >> 6;      // 0..3 -> cols wv*80
  const int lane = tid & 63;
  const int l16  = lane & 15;
  const int lhi  = lane >> 4;     // 0..3
  const int bm   = blockIdx.x * BM;
  const int wvn  = wv * 80;

  // A staging: thread = (row rA = tid>>1, k-half hA = tid&1), 16 fp32 = 64B
  const int rA = tid >> 1, hA = tid & 1;
  const float* xrowA = x + (size_t)(bm + rA) * KDIM;

  // B staging (5 chunks/thread, 1280 exact): r9 scheme
  int bRow[5], bQg[5];
  #pragma unroll
  for (int i = 0; i < 5; ++i) {
    int s = tid + i * NTHR;
    bRow[i] = s >> 2;
    bQg[i]  = (s & 3) ^ (bRow[i] & 3);
  }

  f32x4 av[4];
  auto aload = [&](int t) {
    int k0 = (t < NSTEP) ? t * BK : 0;
    int kk = k0 + hA * 16;
    if (kk > KDIM - 16) kk = KDIM - 16;   // t=24,hA=1: safe dup; B zero-pad kills it
    const float* g = xrowA + kk;
    av[0] = *reinterpret_cast<const f32x4*>(g);
    av[1] = *reinterpret_cast<const f32x4*>(g + 4);
    av[2] = *reinterpret_cast<const f32x4*>(g + 8);
    av[3] = *reinterpret_cast<const f32x4*>(g + 12);
  };
  auto cvtwrite = [&](int t) {
    u16* Ab = lds + (t % 3) * AU + rA * ASTR + hA * 16;
    u32x4 q0 = { pk2(av[0][0], av[0][1]), pk2(av[0][2], av[0][3]),
                 pk2(av[1][0], av[1][1]), pk2(av[1][2], av[1][3]) };
    u32x4 q1 = { pk2(av[2][0], av[2][1]), pk2(av[2][2], av[2][3]),
                 pk2(av[3][0], av[3][1]), pk2(av[3][2], av[3][3]) };
    *reinterpret_cast<u32x4*>(Ab)     = q0;
    *reinterpret_cast<u32x4*>(Ab + 8) = q1;
  };
  auto stageB = [&](int t) {
    char* base = (char*)(lds + BBASEU + (t & 1) * BU);
    int k0 = (t < NSTEP) ? t * BK : 0;
    #pragma unroll
    for (int i = 0; i < 5; ++i)
      gll16(weff + (size_t)bRow[i] * KP + k0 + bQg[i] * 8,
            base + (tid + i * NTHR) * 16);
  };

  f32x4 acc[8][5];
  #pragma unroll
  for (int mi = 0; mi < 8; ++mi)
    #pragma unroll
    for (int ni = 0; ni < 5; ++ni)
      acc[mi][ni] = (f32x4){0.f, 0.f, 0.f, 0.f};

  auto compute = [&](int t) {
    const u16* Ab = lds + (t % 3) * AU;
    const u16* Bb = lds + BBASEU + (t & 1) * BU;
    bf16x8 bfr[5];
    #pragma unroll
    for (int ni = 0; ni < 5; ++ni) {
      int n = wvn + ni * 16 + l16;
      int slot = n * 4 + (lhi ^ (n & 3));
      bfr[ni] = *reinterpret_cast<const bf16x8*>(Bb + slot * 8);
    }
    #pragma unroll
    for (int mi = 0; mi < 8; ++mi) {
      int R = mi * 16 + l16;
      bf16x8 am = *reinterpret_cast<const bf16x8*>(Ab + R * ASTR + lhi * 8);
      #pragma unroll
      for (int ni = 0; ni < 5; ++ni)
        acc[mi][ni] = __builtin_amdgcn_mfma_f32_16x16x32_bf16(am, bfr[ni], acc[mi][ni], 0, 0, 0);
    }
  };

  // ---- prologue: A(0),A(1) -> LDS; B(0) staged ----
  aload(0);
  __builtin_amdgcn_sched_barrier(0);
  asm volatile("s_waitcnt vmcnt(0)" ::: "memory");
  cvtwrite(0);
  aload(1);
  __builtin_amdgcn_sched_barrier(0);
  stageB(0);
  __builtin_amdgcn_sched_barrier(0);
  asm volatile("s_waitcnt vmcnt(5)" ::: "memory");   // drain A(1) loads; keep B(0)
  cvtwrite(1);
  asm volatile("s_waitcnt vmcnt(0) lgkmcnt(0)" ::: "memory");
  __builtin_amdgcn_s_barrier();
  __builtin_amdgcn_sched_barrier(0);

  // ---- main loop: 25 steps, one barrier/step, A loads get a full-step budget ----
  for (int t = 0; t < NSTEP; ++t) {
    aload(t + 2);                      // 4 dwordx4 -> regs (for t+2)
    __builtin_amdgcn_sched_barrier(0);
    stageB(t + 1);                     // 5 gll (dummy at t=24)
    __builtin_amdgcn_sched_barrier(0);
    compute(t);                        // 13 ds_read_b128 + 40 MFMA
    __builtin_amdgcn_sched_barrier(0);
    asm volatile("s_waitcnt vmcnt(5)" ::: "memory");  // drain the 4 A loads only
    cvtwrite(t + 2);                   // 8 pk2 + 2 ds_write_b128
    __builtin_amdgcn_sched_barrier(0);
    asm volatile("s_waitcnt vmcnt(0) lgkmcnt(0)" ::: "memory");  // B landed long ago
    __builtin_amdgcn_s_barrier();
    __builtin_amdgcn_sched_barrier(0);
  }
  __syncthreads();

  // ---- epilogue: h1 = relu(acc + b1); out = h1 @ w2 + b2, 2 passes of 64 rows ----
  u16* H1  = lds;                  // [64][328] = 20992 u16
  u16* W2T = lds + 20992;          // [16][328] = 5248 u16 (ends 52480 B <= 68608)

  for (int i = tid; i < 16 * NP; i += NTHR) {
    int d = i / NP, n = i - (i / NP) * NP;
    float v = (d < DDIM && n < NDIM) ? w2[n * DDIM + d] : 0.f;
    W2T[d * H1STR + n] = f2bf(v);
  }
  float biasv[5];
  #pragma unroll
  for (int ni = 0; ni < 5; ++ni) {
    int col = wvn + ni * 16 + l16;
    biasv[ni] = (col < NDIM) ? b1[col] : 0.f;
  }

  #pragma unroll
  for (int p = 0; p < 2; ++p) {
    #pragma unroll
    for (int mj = 0; mj < 4; ++mj) {
      int mi = p * 4 + mj;
      #pragma unroll
      for (int ni = 0; ni < 5; ++ni) {
        int col = wvn + ni * 16 + l16;
        int rb  = mj * 16 + lhi * 4;
        #pragma unroll
        for (int r = 0; r < 4; ++r) {
          float h = acc[mi][ni][r] + biasv[ni];
          H1[(rb + r) * H1STR + col] = f2bf(fmaxf(h, 0.f));
        }
      }
    }
    __syncthreads();                   // H1 (and W2T on p==0) visible
    {                                  // 4 waves x 16 rows = 64 rows
      f32x4 a2c = (f32x4){0.f, 0.f, 0.f, 0.f};
      #pragma unroll
      for (int ks = 0; ks < NP / 32; ++ks) {
        bf16x8 a2 = *reinterpret_cast<const bf16x8*>(
            H1 + (wv * 16 + l16) * H1STR + ks * 32 + lhi * 8);
        bf16x8 bw = *reinterpret_cast<const bf16x8*>(
            W2T + l16 * H1STR + ks * 32 + lhi * 8);
        a2c = __builtin_amdgcn_mfma_f32_16x16x32_bf16(a2, bw, a2c, 0, 0, 0);
      }
      if (l16 < DDIM) {
        float bb = b2[l16];
        #pragma unroll
        for (int r = 0; r < 4; ++r) {
          int row = bm + p * 64 + wv * 16 + lhi * 4 + r;
          out[(size_t)row * DDIM + l16] = a2c[r] + bb;
        }
      }
    }
    __syncthreads();                   // before next pass overwrites H1
  }
}

extern "C" void kernel_launch(void* const* d_in, const int* in_sizes, int n_in,
                              void* d_out, int out_size, void* d_ws, size_t ws_size,
                              hipStream_t stream) {
  const float* x  = (const float*)d_in[0];
  const float* cw = (const float*)d_in[1];
  const float* w1 = (const float*)d_in[2];
  const float* b1 = (const float*)d_in[3];
  const float* w2 = (const float*)d_in[4];
  const float* b2 = (const float*)d_in[5];
  float* out = (float*)d_out;
  u16* weff = (u16*)d_ws;   // 320*800*2 = 512000 bytes

  hipLaunchKernelGGL(build_weff, dim3((NP * KP + 255) / 256), dim3(256), 0, stream,
                     cw, w1, weff);
  hipLaunchKernelGGL(fused_mlp, dim3(NROW / BM), dim3(NTHR), 0, stream,
                     x, b1, w2, b2, weff, out);
}

// Round 16
// 61.702 us; speedup vs baseline: 1.6145x; 1.4450x over previous
//
#include <hip/hip_runtime.h>
#include <hip/hip_bf16.h>

typedef __attribute__((ext_vector_type(8))) short bf16x8;
typedef __attribute__((ext_vector_type(4))) float f32x4;
typedef __attribute__((ext_vector_type(4))) unsigned int u32x4;
typedef unsigned short u16;
typedef unsigned int u32;

static constexpr int KDIM  = 784;   // 28*28
static constexpr int KP    = 800;   // K padded (weff zero-pads k>=784 and n>=300)
static constexpr int NDIM  = 300;
static constexpr int NP    = 320;
static constexpr int DDIM  = 10;
static constexpr int BM    = 256;   // rows per block -> grid = 256 = 1 block/CU
static constexpr int BK    = 32;
static constexpr int NSTEP = 25;
static constexpr int H1STR = 328;
static constexpr int NROW  = 65536;
static constexpr int NTHR  = 512;   // 8 waves: 2m x 4n
// LDS bytes: A fp32 3 x 32768 @ 0; B bf16 2 x 20480 @ 98304. Total 139264.
static constexpr int ABYTES = 32768;
static constexpr int BBYTES = 20480;
static constexpr int BBASE  = 98304;

__device__ __forceinline__ u16 f2bf(float f) {
  unsigned u = __builtin_bit_cast(unsigned, f);
  u += 0x7fffu + ((u >> 16) & 1u);   // RNE
  return (u16)(u >> 16);
}
__device__ __forceinline__ u32 pk2(float a, float b) {
  u32 r;
  asm("v_cvt_pk_bf16_f32 %0, %1, %2" : "=v"(r) : "v"(a), "v"(b));
  return r;
}
__device__ __forceinline__ void gll16(const void* g, void* l) {
  __builtin_amdgcn_global_load_lds(
      (const __attribute__((address_space(1))) void*)g,
      (__attribute__((address_space(3))) void*)l, 16, 0, 0);
}

// ---- Kernel A: fold conv into first linear layer; weff_t[n][k] bf16, zero-padded ----
__global__ void build_weff(const float* __restrict__ cw,
                           const float* __restrict__ w1,
                           u16* __restrict__ weff) {
  int idx = blockIdx.x * 256 + threadIdx.x;
  if (idx >= NP * KP) return;
  int n = idx / KP;
  int k = idx - n * KP;
  float acc = 0.f;
  if (n < NDIM && k < KDIM) {
    int r = k / 28, c = k - (k / 28) * 28;
    #pragma unroll
    for (int dr = 0; dr < 3; ++dr) {
      int orr = r - dr;
      if ((unsigned)orr < 26u) {
        #pragma unroll
        for (int dc = 0; dc < 3; ++dc) {
          int oc = c - dc;
          if ((unsigned)oc < 26u)
            acc += cw[dr * 3 + dc] * w1[(orr * 26 + oc) * NDIM + n];
        }
      }
    }
  }
  weff[n * KP + k] = f2bf(acc);
}

// ---- Kernel B: out = relu(x @ Weff + b1) @ w2 + b2 ----
// 512 thr / 8 waves (2m x 4n); per wave 128 rows x 80 cols = 8x5 16x16x32 frags.
// Grid = 256 blocks = exactly 1/CU; weff L2 traffic 128MB total.
// All staging via global_load_lds, uniform 7/thread/step (4 A + 3 B):
//   A (x fp32): 3 buffers, staged 2 steps ahead (~1.5 step-times of latency)
//   B (weff bf16, L2-resident): 2 buffers, 1 step ahead
// Counted s_waitcnt vmcnt(4) before each barrier keeps A(t+2) in flight.
// XOR-swizzled chunk maps: global reads line-coalesced, LDS banks even.
__global__ void __launch_bounds__(NTHR, 2)
fused_mlp(const float* __restrict__ x, const float* __restrict__ b1,
          const float* __restrict__ w2, const float* __restrict__ b2,
          const u16* __restrict__ weff, float* __restrict__ out) {
  __shared__ __align__(16) u16 lds[69632];   // 139264 B -> 1 block/CU

  const int tid  = threadIdx.x;
  const int wv   = tid >> 6;
  const int lane = tid & 63;
  const int l16  = lane & 15;
  const int lhi  = lane >> 4;     // 0..3
  const int wm   = wv >> 2;       // 0..1 -> rows wm*128
  const int wn   = wv & 3;        // 0..3 -> cols wn*80
  const int bm   = blockIdx.x * BM;
  const int wvn  = wn * 80;

  // --- A staging (4 chunks/thread): slot s in [0,2048), row=s>>3 (8x16B/row),
  //     global chunk qg = (s&7) ^ (row&7)  (line-coalesced + bank-even)
  int aRow[4], aQg[4];
  #pragma unroll
  for (int it = 0; it < 4; ++it) {
    int s = tid + it * NTHR;
    aRow[it] = s >> 3;
    aQg[it]  = (s & 7) ^ (aRow[it] & 7);
  }
  // --- B staging (3 chunks/thread, slots 1024..1279 written twice benignly):
  //     slot s in [0,1280), row=s>>2, c=s&3, qg = c ^ (row&3)
  int bRow[3], bQg[3];
  #pragma unroll
  for (int i = 0; i < 3; ++i) {
    int s = (i < 2) ? (tid + i * NTHR) : (1024 + (tid & 255));
    bRow[i] = s >> 2;
    bQg[i]  = (s & 3) ^ (bRow[i] & 3);
  }

  auto stageA = [&](int bufi, int t) {
    char* base = (char*)lds + bufi * ABYTES;
    int k0 = (t < NSTEP) ? t * BK : 0;
    #pragma unroll
    for (int it = 0; it < 4; ++it) {
      int kof = k0 + aQg[it] * 4;
      if (kof >= KDIM) kof = aQg[it] * 4;   // t=24 pad chunks: finite garbage, B=0
      gll16(x + (size_t)(bm + aRow[it]) * KDIM + kof,
            base + (tid + it * NTHR) * 16);
    }
  };
  auto stageB = [&](int bufi, int t) {
    char* base = (char*)lds + BBASE + bufi * BBYTES;
    int k0 = (t < NSTEP) ? t * BK : 0;
    #pragma unroll
    for (int i = 0; i < 3; ++i) {
      int s = (i < 2) ? (tid + i * NTHR) : (1024 + (tid & 255));
      gll16(weff + (size_t)bRow[i] * KP + k0 + bQg[i] * 8, base + s * 16);
    }
  };

  f32x4 acc[8][5];
  #pragma unroll
  for (int mi = 0; mi < 8; ++mi)
    #pragma unroll
    for (int ni = 0; ni < 5; ++ni)
      acc[mi][ni] = (f32x4){0.f, 0.f, 0.f, 0.f};

  auto compute = [&](int abufi, int bbufi) {
    const f32x4* Af = (const f32x4*)((char*)lds + abufi * ABYTES);
    const u16*   Bb = (const u16*)((char*)lds + BBASE + bbufi * BBYTES);
    bf16x8 bfr[5];
    #pragma unroll
    for (int ni = 0; ni < 5; ++ni) {
      int n = wvn + ni * 16 + l16;
      int slot = n * 4 + (lhi ^ (n & 3));
      bfr[ni] = *reinterpret_cast<const bf16x8*>(Bb + slot * 8);
    }
    #pragma unroll
    for (int mi = 0; mi < 8; ++mi) {
      int R = wm * 128 + mi * 16 + l16;
      f32x4 a0 = Af[R * 8 + ((2 * lhi)     ^ (R & 7))];
      f32x4 a1 = Af[R * 8 + ((2 * lhi + 1) ^ (R & 7))];
      u32x4 amu = { pk2(a0[0], a0[1]), pk2(a0[2], a0[3]),
                    pk2(a1[0], a1[1]), pk2(a1[2], a1[3]) };
      bf16x8 am = __builtin_bit_cast(bf16x8, amu);
      #pragma unroll
      for (int ni = 0; ni < 5; ++ni)
        acc[mi][ni] = __builtin_amdgcn_mfma_f32_16x16x32_bf16(am, bfr[ni], acc[mi][ni], 0, 0, 0);
    }
  };

  // ---- prologue: A(0), B(0), A(1) issued; keep A(1) in flight ----
  stageA(0, 0);
  stageB(0, 0);
  stageA(1, 1);
  asm volatile("s_waitcnt vmcnt(4)" ::: "memory");   // drain A(0),B(0); keep A(1)
  __builtin_amdgcn_s_barrier();
  __builtin_amdgcn_sched_barrier(0);

  // ---- main loop: 25 uniform steps, counted vmcnt, one barrier/step ----
  for (int t = 0; t < NSTEP; ++t) {
    stageB((t + 1) & 1, t + 1);        // 3 gll (dummy at t=24)
    stageA((t + 2) % 3, t + 2);        // 4 gll (dummy at t>=23)
    __builtin_amdgcn_sched_barrier(0);
    compute(t % 3, t & 1);
    __builtin_amdgcn_sched_barrier(0);
    asm volatile("s_waitcnt vmcnt(4)" ::: "memory");  // drain A(t+1),B(t+1); keep A(t+2)
    __builtin_amdgcn_s_barrier();
    __builtin_amdgcn_sched_barrier(0);
  }
  __syncthreads();    // full drain (incl. dummy stages) before LDS overlay

  // ---- epilogue: h1 = relu(acc + b1); out = h1 @ w2 + b2, 4 passes of 64 rows ----
  u16* H1  = lds;                  // [64][328] = 20992 u16
  u16* W2T = lds + 20992;          // [16][328] = 5248 u16 (52480 B <= 139264)

  for (int i = tid; i < 16 * NP; i += NTHR) {
    int d = i / NP, n = i - (i / NP) * NP;
    float v = (d < DDIM && n < NDIM) ? w2[n * DDIM + d] : 0.f;
    W2T[d * H1STR + n] = f2bf(v);
  }
  float biasv[5];
  #pragma unroll
  for (int ni = 0; ni < 5; ++ni) {
    int col = wvn + ni * 16 + l16;
    biasv[ni] = (col < NDIM) ? b1[col] : 0.f;
  }

  #pragma unroll
  for (int p = 0; p < 4; ++p) {
    if (wm == (p >> 1)) {
      #pragma unroll
      for (int mj = 0; mj < 4; ++mj) {
        int mi = (p & 1) * 4 + mj;
        #pragma unroll
        for (int ni = 0; ni < 5; ++ni) {
          int col = wvn + ni * 16 + l16;
          int rb  = mj * 16 + lhi * 4;
          #pragma unroll
          for (int r = 0; r < 4; ++r) {
            float h = acc[mi][ni][r] + biasv[ni];
            H1[(rb + r) * H1STR + col] = f2bf(fmaxf(h, 0.f));
          }
        }
      }
    }
    __syncthreads();               // H1 (and W2T on p==0) visible
    if (wv < 4) {
      f32x4 a2c = (f32x4){0.f, 0.f, 0.f, 0.f};
      #pragma unroll
      for (int ks = 0; ks < NP / 32; ++ks) {
        bf16x8 a2 = *reinterpret_cast<const bf16x8*>(
            H1 + (wv * 16 + l16) * H1STR + ks * 32 + lhi * 8);
        bf16x8 bw = *reinterpret_cast<const bf16x8*>(
            W2T + l16 * H1STR + ks * 32 + lhi * 8);
        a2c = __builtin_amdgcn_mfma_f32_16x16x32_bf16(a2, bw, a2c, 0, 0, 0);
      }
      if (l16 < DDIM) {
        float bb = b2[l16];
        #pragma unroll
        for (int r = 0; r < 4; ++r) {
          int row = bm + p * 64 + wv * 16 + lhi * 4 + r;
          out[(size_t)row * DDIM + l16] = a2c[r] + bb;
        }
      }
    }
    __syncthreads();               // before next pass overwrites H1
  }
}

extern "C" void kernel_launch(void* const* d_in, const int* in_sizes, int n_in,
                              void* d_out, int out_size, void* d_ws, size_t ws_size,
                              hipStream_t stream) {
  const float* x  = (const float*)d_in[0];
  const float* cw = (const float*)d_in[1];
  const float* w1 = (const float*)d_in[2];
  const float* b1 = (const float*)d_in[3];
  const float* w2 = (const float*)d_in[4];
  const float* b2 = (const float*)d_in[5];
  float* out = (float*)d_out;
  u16* weff = (u16*)d_ws;   // 320*800*2 = 512000 bytes

  hipLaunchKernelGGL(build_weff, dim3((NP * KP + 255) / 256), dim3(256), 0, stream,
                     cw, w1, weff);
  hipLaunchKernelGGL(fused_mlp, dim3(NROW / BM), dim3(NTHR), 0, stream,
                     x, b1, w2, b2, weff, out);
}